// Round 14
// baseline (379.829 us; speedup 1.0000x reference)
//
#include <hip/hip_runtime.h>
#include <hip/hip_bf16.h>

#define SEQ   101
#define BATCH 16384
#define INP   9
#define HID   32
#define NOUT  3
#define HSlin 3232          // HID*SEQ
#define SB    (SEQ * BATCH) // flattened (s,b) cols

typedef __attribute__((ext_vector_type(8))) _Float16 half8;   // 8 fp16 (4 VGPRs)
typedef __attribute__((ext_vector_type(8))) short short8;
typedef __attribute__((ext_vector_type(4))) float f32x4;      // MFMA C/D
typedef __attribute__((ext_vector_type(2))) float f32x2;      // v_pk_* pairs
typedef __attribute__((ext_vector_type(4))) unsigned u32x4;

#define LOG2E   1.4426950408889634f
#define N2LOG2E (-2.8853900817779268f)

// pack two f32 -> half2 in one v_cvt_pkrtz_f16_f32
__device__ __forceinline__ unsigned pkh(float a, float b) {
    return __builtin_bit_cast(unsigned, __builtin_amdgcn_cvt_pkrtz(a, b));
}
// DPP row_ror:8 — within each 16-lane row, lane i <-> lane i^8
__device__ __forceinline__ unsigned dpp8u(unsigned v) {
    return (unsigned)__builtin_amdgcn_mov_dpp((int)v, 0x128, 0xF, 0xF, true);
}
// lane i <-> i^4 via ds_swizzle BitMode: offset = (xor=4)<<10 | and=0x1F
__device__ __forceinline__ unsigned swz4u(unsigned v) {
    return (unsigned)__builtin_amdgcn_ds_swizzle((int)v, 0x101F);
}

// Swapped-operand fp16 scheme: gates^T = W * [x|1|h]^T.
// Weights pre-scaled by log2e (i,f,o) / 2*log2e (g) so activations use raw exp2.
// h k-permutation: pi(8g+j) = 4g + (j&3) + 16*(j>>2).
// x map: k=0..8 -> W_ih col k; k==9 -> combined bias (x supplies 1.0); k>=10 -> 0.
__global__ void prep_kernel(const float* __restrict__ W_ih, const float* __restrict__ W_hh,
                            const float* __restrict__ b_ih, const float* __restrict__ b_hh,
                            unsigned short* __restrict__ whh16, unsigned short* __restrict__ wih16) {
    int tid = threadIdx.x;            // 0..511 : t = tid>>6, l = tid&63
    int l   = tid & 63;
    int t   = tid >> 6;
    int row = l & 15;                 // gate-in-tile
    int g   = l >> 4;
    int gate = 16 * t + row;
    float sc = ((gate >> 5) == 2) ? (2.f * LOG2E) : LOG2E;    // g-gate: tanh needs e^{-2g}
    for (int j = 0; j < 8; ++j) {
        int u = 4 * g + (j & 3) + 16 * (j >> 2);     // pi(8g+j)
        _Float16 wh = (_Float16)(W_hh[gate * HID + u] * sc);
        whh16[tid * 8 + j] = __builtin_bit_cast(unsigned short, wh);
        int k = 8 * g + j;
        float wv;
        if      (k < INP)  wv = W_ih[gate * INP + k] * sc;
        else if (k == INP) wv = (b_ih[gate] + b_hh[gate]) * sc;   // bias slot
        else               wv = 0.f;
        _Float16 wi = (_Float16)wv;
        wih16[tid * 8 + j] = __builtin_bit_cast(unsigned short, wi);
    }
}

// Emit staged W_lin partials (base psb = s*BATCH + b0, 4 cols).
// Merge copies (xor4,xor8) + g-groups (xor16,xor32); off critical path.
template<bool PLANES>
__device__ __forceinline__ void emit_prev(float p0, float p1, float p2,
                                          unsigned psb, float* __restrict__ dataout,
                                          int lane, int c) {
    p0 += __shfl_xor(p0, 4);  p1 += __shfl_xor(p1, 4);  p2 += __shfl_xor(p2, 4);
    p0 += __shfl_xor(p0, 8);  p1 += __shfl_xor(p1, 8);  p2 += __shfl_xor(p2, 8);
    p0 += __shfl_xor(p0, 16); p1 += __shfl_xor(p1, 16); p2 += __shfl_xor(p2, 16);
    p0 += __shfl_xor(p0, 32); p1 += __shfl_xor(p1, 32); p2 += __shfl_xor(p2, 32);
    if (PLANES) {
        if (lane < 4) {
            unsigned blk = psb + (unsigned)lane;
            dataout[0 * SB + blk] = p0;
            dataout[1 * SB + blk] = p1;
            dataout[2 * SB + blk] = p2;
        }
    } else {
        // fallback: <=2 output rows across the 4 cols; butterfly + lane-0 atomics
        unsigned blk  = psb + (unsigned)c;
        unsigned r    = blk / 101u;
        unsigned rmin = psb / 101u;
        bool low = (r == rmin);
        float a0 = low ? p0 : 0.f, a1 = low ? p1 : 0.f, a2 = low ? p2 : 0.f;
        float d0 = low ? 0.f : p0, d1 = low ? 0.f : p1, d2 = low ? 0.f : p2;
#pragma unroll
        for (int m = 1; m < 4; m <<= 1) {
            a0 += __shfl_xor(a0, m); a1 += __shfl_xor(a1, m); a2 += __shfl_xor(a2, m);
            d0 += __shfl_xor(d0, m); d1 += __shfl_xor(d1, m); d2 += __shfl_xor(d2, m);
        }
        int anyhi = __any(!low && lane < 4);
        if (lane == 0) {
            atomicAdd(&dataout[rmin * 3 + 0], a0);
            atomicAdd(&dataout[rmin * 3 + 1], a1);
            atomicAdd(&dataout[rmin * 3 + 2], a2);
            if (anyhi) {
                atomicAdd(&dataout[(rmin + 1u) * 3 + 0], d0);
                atomicAdd(&dataout[(rmin + 1u) * 3 + 1], d1);
                atomicAdd(&dataout[(rmin + 1u) * 3 + 2], d2);
            }
        }
    }
}

// One INDEPENDENT wave per 4 batch rows (cols 4..15 duplicate 0..3) — grid
// 4096 = 4 waves/SIMD. 4-way activation split: copy cp=(lane>>2)&3 handles
// units {16*ht + 4g + 2*qp + {0,1}} (ht=cp>>1, qp=cp&1). h B-frag gathered
// via 1 ds_swizzle(xor4) + 2 DPP(ror8). Bias folded into x-MFMA K-slot 9.
template<bool PLANES>
__global__ __launch_bounds__(64, 4) void lstm_kernel(
    const float* __restrict__ x,                 // [SEQ][BATCH][INP]
    const unsigned short* __restrict__ whh_g,    // [8][64][8] fp16 A-frags
    const unsigned short* __restrict__ wih_g,    // [8][64][8] fp16 A-frags (+bias k=9)
    const float* __restrict__ W_lin,             // [NOUT][HSlin]
    float* __restrict__ dataout)                 // planes [3][SB] (or accp fallback)
{
    const int lane = threadIdx.x;
    const int c    = lane & 3;         // real batch col
    const int cp   = (lane >> 2) & 3;  // copy id
    const bool htb = (cp & 2) != 0;    // unit half (ht)
    const bool qpb = (cp & 1) != 0;    // q-pair within half
    const int g    = lane >> 4;
    const int b0   = blockIdx.x * 4;
    const int b    = b0 + c;

    // Static A-fragments (live across all steps)
    half8 whh[8], xw[8];
#pragma unroll
    for (int t = 0; t < 8; ++t) {
        whh[t] = __builtin_bit_cast(half8, *reinterpret_cast<const short8*>(whh_g + (t * 64 + lane) * 8));
        xw[t]  = __builtin_bit_cast(half8, *reinterpret_cast<const short8*>(wih_g + (t * 64 + lane) * 8));
    }

    const bool g0 = (g == 0), g1 = (g == 1);

    f32x2 cs = {0.f, 0.f};             // c-state of my 2 units
    f32x2 ho = {0.f, 0.f};             // h of my 2 units
    u32x4 bhv = {0u, 0u, 0u, 0u};      // packed fp16 h B-frag (persistent)
    float xv[9];
    {
        const float* xp = x + (size_t)b * INP;           // s = 0
#pragma unroll
        for (int i = 0; i < 9; ++i) xv[i] = xp[i];
    }

    // running W_lin column: slot = (s*BATCH + b) mod 101; BATCH ≡ 22 (mod 101)
    unsigned rr   = (unsigned)b / 101u;
    unsigned slot = (unsigned)b - rr * 101u;

    // my units: u0 = 16*ht + 4g + 2*qp, u1 = u0+1 (contiguous)
    const int u0 = (htb ? 16 : 0) + 4 * g + (qpb ? 2 : 0);

    float pp0 = 0.f, pp1 = 0.f, pp2 = 0.f;       // staged W_lin partials
    unsigned psb = 0;

#pragma unroll 1
    for (int s = 0; s < SEQ; ++s) {
        // (0) this step's W_lin weights — my 2 units x 3 planes (float2 each)
        const float* wl = W_lin + slot * HID + u0;
        float2 w0 = *(const float2*)(wl);
        float2 w1 = *(const float2*)(wl + HSlin);
        float2 w2 = *(const float2*)(wl + 2 * HSlin);

        // (1) fp16 x B-fragment: g0 -> x0..x7 (k0-7); g1 -> x8, 1.0 (k8-9)
        half8 xa;
        {
            unsigned x01 = pkh(xv[0], xv[1]), x23 = pkh(xv[2], xv[3]);
            unsigned x45 = pkh(xv[4], xv[5]), x67 = pkh(xv[6], xv[7]);
            unsigned x81 = pkh(xv[8], 1.0f);
            u32x4 xt;
            xt[0] = g0 ? x01 : (g1 ? x81 : 0u);
            xt[1] = g0 ? x23 : 0u;
            xt[2] = g0 ? x45 : 0u;
            xt[3] = g0 ? x67 : 0u;
            xa = __builtin_bit_cast(half8, xt);
        }
        // (2) gates^T: 8 tiles x 2 MFMA (x-proj includes bias via k=9; C=0)
        half8 bh = __builtin_bit_cast(half8, bhv);
        const f32x4 zz = {0.f, 0.f, 0.f, 0.f};
        f32x4 acc[8];
#pragma unroll
        for (int t = 0; t < 8; ++t) {
            acc[t] = __builtin_amdgcn_mfma_f32_16x16x32_f16(xw[t], xa, zz, 0, 0, 0);
            acc[t] = __builtin_amdgcn_mfma_f32_16x16x32_f16(whh[t], bh, acc[t], 0, 0, 0);
        }
        // (3) previous step's reduce + stores — hides under MFMA latency
        if (s > 0) emit_prev<PLANES>(pp0, pp1, pp2, psb, dataout, lane, c);

        // (4) prefetch next step's x
        float xn[9];
        if (s < SEQ - 1) {
            const float* xpn = x + ((size_t)(s + 1) * BATCH + b) * INP;
#pragma unroll
            for (int i = 0; i < 9; ++i) xn[i] = xpn[i];
        }

        // (5) my 2 gates-of-each-type via static vector selects (no runtime idx)
        f32x4 vI = htb ? acc[1] : acc[0];
        f32x4 vF = htb ? acc[3] : acc[2];
        f32x4 vG = htb ? acc[5] : acc[4];
        f32x4 vO = htb ? acc[7] : acc[6];
        f32x2 aI = qpb ? (f32x2){vI[2], vI[3]} : (f32x2){vI[0], vI[1]};
        f32x2 aF = qpb ? (f32x2){vF[2], vF[3]} : (f32x2){vF[0], vF[1]};
        f32x2 aG = qpb ? (f32x2){vG[2], vG[3]} : (f32x2){vG[0], vG[1]};
        f32x2 aO = qpb ? (f32x2){vO[2], vO[3]} : (f32x2){vO[0], vO[1]};

        // (6) activations (1 pair):
        //     c' = [c*(1+ei)(1+eg) + (1-eg)(1+ef)] / [(1+ef)(1+ei)(1+eg)]
        //     h  = (1-ec) / ((1+eo)(1+ec)),  ec = exp2(c' * -2log2e)
        {
            f32x2 ef = {__builtin_amdgcn_exp2f(-aF.x), __builtin_amdgcn_exp2f(-aF.y)};
            f32x2 ei = {__builtin_amdgcn_exp2f(-aI.x), __builtin_amdgcn_exp2f(-aI.y)};
            f32x2 eg = {__builtin_amdgcn_exp2f(-aG.x), __builtin_amdgcn_exp2f(-aG.y)};
            f32x2 pf = ef + 1.f;
            f32x2 A  = (ei + 1.f) * (eg + 1.f);
            f32x2 num = cs * A + (1.f - eg) * pf;
            f32x2 den = pf * A;
            f32x2 rd = {__builtin_amdgcn_rcpf(den.x), __builtin_amdgcn_rcpf(den.y)};
            f32x2 cn = num * rd;
            cs = cn;
            f32x2 eo = {__builtin_amdgcn_exp2f(-aO.x), __builtin_amdgcn_exp2f(-aO.y)};
            f32x2 ec = {__builtin_amdgcn_exp2f(cn.x * N2LOG2E), __builtin_amdgcn_exp2f(cn.y * N2LOG2E)};
            f32x2 dd = (eo + 1.f) * (ec + 1.f);
            f32x2 rh = {__builtin_amdgcn_rcpf(dd.x), __builtin_amdgcn_rcpf(dd.y)};
            ho = (1.f - ec) * rh;
        }
        // (6b) gather the 4 copy-words into the full B-frag.
        //      word w holds units {4g + 2*(w&1) + 16*(w>>1) + {0,1}} -> w == cp.
        {
            unsigned own = pkh(ho.x, ho.y);
            unsigned t1 = swz4u(own);            // word cp^1
            unsigned t2 = dpp8u(own);            // word cp^2
            unsigned t3 = dpp8u(t1);             // word cp^3
            unsigned e  = qpb ? t1 : own;        // even word of my pair-group
            unsigned o  = qpb ? own : t1;
            unsigned e2 = qpb ? t3 : t2;         // even word of other pair-group
            unsigned o2 = qpb ? t2 : t3;
            bhv[0] = htb ? e2 : e;
            bhv[1] = htb ? o2 : o;
            bhv[2] = htb ? e : e2;
            bhv[3] = htb ? o : o2;
        }
        if (s < SEQ - 1) {
#pragma unroll
            for (int i = 0; i < 9; ++i) xv[i] = xn[i];
        }

        // (7) this step's W_lin partials — my 2 units
        pp0 = w0.x * ho.x + w0.y * ho.y;
        pp1 = w1.x * ho.x + w1.y * ho.y;
        pp2 = w2.x * ho.x + w2.y * ho.y;
        psb = ((unsigned)s << 14) + (unsigned)b0;            // s*BATCH + b0

        slot += 22u;                                         // (+BATCH) mod 101
        slot = (slot >= 101u) ? (slot - 101u) : slot;
    }
    // epilogue: emit for s = SEQ-1
    emit_prev<PLANES>(pp0, pp1, pp2, psb, dataout, lane, c);
}

// Plane path: one wave per output row sums its 101 contiguous cols.
__global__ void finalize_planes(const float* __restrict__ planes, const float* __restrict__ b_lin,
                                float* __restrict__ out) {
    int wid = (blockIdx.x * blockDim.x + threadIdx.x) >> 6;   // row 0..16383
    int l   = threadIdx.x & 63;
    float v[3];
#pragma unroll
    for (int o = 0; o < 3; ++o) {
        const float* p = planes + (size_t)o * SB + (size_t)wid * 101;
        float t = p[l] + ((l < 37) ? p[l + 64] : 0.f);
#pragma unroll
        for (int m = 1; m < 64; m <<= 1) t += __shfl_xor(t, m);
        v[o] = t;
    }
    if (l == 0) {
        out[wid * 3 + 0] = v[0] + b_lin[0];
        out[wid * 3 + 1] = v[1] + b_lin[1];
        out[wid * 3 + 2] = v[2] + b_lin[2];
    }
}

__global__ void finalize_acc(const float* __restrict__ acc, const float* __restrict__ b_lin,
                             float* __restrict__ out) {
    int i = blockIdx.x * blockDim.x + threadIdx.x;
    if (i < BATCH * NOUT) {
        int r = i / 3;
        int o = i - r * 3;
        out[i] = acc[i] + b_lin[o];
    }
}

extern "C" void kernel_launch(void* const* d_in, const int* in_sizes, int n_in,
                              void* d_out, int out_size, void* d_ws, size_t ws_size,
                              hipStream_t stream) {
    const float* x     = (const float*)d_in[0];
    const float* W_ih  = (const float*)d_in[1];
    const float* W_hh  = (const float*)d_in[2];
    const float* b_ih  = (const float*)d_in[3];
    const float* b_hh  = (const float*)d_in[4];
    const float* W_lin = (const float*)d_in[5];
    const float* b_lin = (const float*)d_in[6];
    float* out = (float*)d_out;

    // ws: whh16[4096]u16 | wih16[4096]u16 | (pad) | data...
    unsigned short* whh16 = (unsigned short*)d_ws;
    unsigned short* wih16 = whh16 + 4096;
    float* data  = (float*)((char*)d_ws + 25600);

    size_t need_planes = 25600 + (size_t)3 * SB * sizeof(float);
    bool planes = ws_size >= need_planes;

    hipLaunchKernelGGL(prep_kernel, dim3(1), dim3(512), 0, stream,
                       W_ih, W_hh, b_ih, b_hh, whh16, wih16);
    if (planes) {
        hipLaunchKernelGGL((lstm_kernel<true>), dim3(BATCH / 4), dim3(64), 0, stream,
                           x, whh16, wih16, W_lin, data);
        hipLaunchKernelGGL(finalize_planes, dim3(BATCH / 4), dim3(256), 0, stream,
                           data, b_lin, out);
    } else {
        hipMemsetAsync(data, 0, 49160 * sizeof(float), stream);
        hipLaunchKernelGGL((lstm_kernel<false>), dim3(BATCH / 4), dim3(64), 0, stream,
                           x, whh16, wih16, W_lin, data);
        hipLaunchKernelGGL(finalize_acc, dim3((BATCH * NOUT + 255) / 256), dim3(256), 0, stream,
                           data, b_lin, out);
    }
}